// Round 3
// baseline (367.502 us; speedup 1.0000x reference)
//
#include <hip/hip_runtime.h>

#define NT 16384
#define DM 4096
#define NE 64
#define TOPK 8
#define NWAVES 8          // waves per workgroup (K-split factor)
#define KCH (DM / NWAVES) // 512 K-elements per wave
#define WIN 16            // k-window per inner step
#define NWIN (KCH / WIN)  // 32 windows
#define RSTRIDE 65        // LDS row stride in floats: (65*l+e)%32 conflict-free

__global__ __launch_bounds__(512, 2) void gate_kernel(
    const float* __restrict__ x,
    const float* __restrict__ W,
    int* __restrict__ out) {

  const int lane = threadIdx.x & 63;
  const int wid  = __builtin_amdgcn_readfirstlane((int)(threadIdx.x >> 6));
  const int tok  = blockIdx.x * 64 + lane;
  const int kbase = wid * KCH;

  // acc must stay in VGPRs: ALL indices compile-time constant, and its
  // address is NEVER taken (R2: float4-punning the array -> scratch, VGPR=52).
  float acc[NE];
#pragma unroll
  for (int e = 0; e < NE; ++e) acc[e] = 0.f;

  const float* xrow = x + (size_t)tok * DM + kbase;

  // double-buffered per-lane x window (16 floats = 4 x float4)
  float4 xa[4], xb[4];
#pragma unroll
  for (int v = 0; v < 4; ++v) xa[v] = ((const float4*)xrow)[v];

  for (int w = 0; w < NWIN; ++w) {
    if (w + 1 < NWIN) {
      const float* xn = xrow + (w + 1) * WIN;
#pragma unroll
      for (int v = 0; v < 4; ++v) xb[v] = ((const float4*)xn)[v];
    }
    const int k0 = kbase + w * WIN;
#pragma unroll
    for (int e = 0; e < NE; ++e) {
      const float4* wv = (const float4*)(W + e * DM + k0); // wave-uniform -> s_load
      float s = 0.f;
#pragma unroll
      for (int v = 0; v < 4; ++v) {
        float4 wf = wv[v];
        s = fmaf(xa[v].x, wf.x, s);
        s = fmaf(xa[v].y, wf.y, s);
        s = fmaf(xa[v].z, wf.z, s);
        s = fmaf(xa[v].w, wf.w, s);
      }
      acc[e] += s; // two-level accumulation for accuracy
    }
#pragma unroll
    for (int v = 0; v < 4; ++v) xa[v] = xb[v];
  }

  // ---- cross-wave K reduction: pairwise tree via LDS (2 slots) ----
  // Element-wise, static indices only: never materialize acc in memory.
  __shared__ float red[2][64][RSTRIDE]; // 2*64*65*4 = 33280 B

  auto dump = [&](int slot) {
#pragma unroll
    for (int e = 0; e < NE; ++e) red[slot][lane][e] = acc[e];
  };
  auto addin = [&](int slot) {
#pragma unroll
    for (int e = 0; e < NE; ++e) acc[e] += red[slot][lane][e];
  };

  // step 1: waves 4,5 -> slots 0,1 ; waves 0,1 absorb
  if (wid == 4) dump(0);
  if (wid == 5) dump(1);
  __syncthreads();
  if (wid == 0) addin(0);
  if (wid == 1) addin(1);
  __syncthreads();
  // step 2: waves 6,7 -> slots 0,1 ; waves 2,3 absorb
  if (wid == 6) dump(0);
  if (wid == 7) dump(1);
  __syncthreads();
  if (wid == 2) addin(0);
  if (wid == 3) addin(1);
  __syncthreads();
  // step 3: waves 2,3 -> slots 0,1 ; waves 0,1 absorb
  if (wid == 2) dump(0);
  if (wid == 3) dump(1);
  __syncthreads();
  if (wid == 0) addin(0);
  if (wid == 1) addin(1);
  __syncthreads();
  // step 4: wave 1 -> slot 0 ; wave 0 absorbs
  if (wid == 1) dump(0);
  __syncthreads();

  if (wid == 0) {
    addin(0);

    // ---- top-8 by repeated argmax (stable: lowest index wins ties) ----
    int idx[TOPK];
#pragma unroll
    for (int p = 0; p < TOPK; ++p) {
      float m = -3.402823466e38f;
      int mi = 0;
#pragma unroll
      for (int e = 0; e < NE; ++e) {
        bool b = acc[e] > m; // strict >, ascending scan => first occurrence
        m  = b ? acc[e] : m;
        mi = b ? e : mi;
      }
      idx[p] = mi;
#pragma unroll
      for (int e = 0; e < NE; ++e)
        acc[e] = (e == mi) ? -3.402823466e38f : acc[e];
    }

    int4* op = (int4*)(out + (size_t)tok * TOPK);
    op[0] = make_int4(idx[0], idx[1], idx[2], idx[3]);
    op[1] = make_int4(idx[4], idx[5], idx[6], idx[7]);
  }
}

extern "C" void kernel_launch(void* const* d_in, const int* in_sizes, int n_in,
                              void* d_out, int out_size, void* d_ws, size_t ws_size,
                              hipStream_t stream) {
  const float* x = (const float*)d_in[0];
  const float* W = (const float*)d_in[1];
  int* out = (int*)d_out;
  (void)in_sizes; (void)n_in; (void)out_size; (void)d_ws; (void)ws_size;

  dim3 grid(NT / 64);   // 256 workgroups, one per 64 tokens
  dim3 block(512);      // 8 waves: K-split
  hipLaunchKernelGGL(gate_kernel, grid, block, 0, stream, x, W, out);
}

// Round 4
// 366.603 us; speedup vs baseline: 1.0025x; 1.0025x over previous
//
#include <hip/hip_runtime.h>

#define NT 16384
#define DM 4096
#define NE 64
#define TOPK 8
#define NWAVES 8          // waves per workgroup (K-split factor)
#define KCH (DM / NWAVES) // 512 K-elements per wave
#define WIN 16            // k-window per inner step
#define NWIN (KCH / WIN)  // 32 windows
#define NEGINF (-3.402823466e38f)

// X-macro over the 64 experts: generates NAMED scalar accumulators so the
// compiler's mem2reg keeps them in VGPRs. (R1-R3: any form of float acc[64]
// ended up in scratch -> VGPR=52, VALUBusy 11%, 520us.)
#define FOR_E(A) A(0) A(1) A(2) A(3) A(4) A(5) A(6) A(7) \
  A(8) A(9) A(10) A(11) A(12) A(13) A(14) A(15) \
  A(16) A(17) A(18) A(19) A(20) A(21) A(22) A(23) \
  A(24) A(25) A(26) A(27) A(28) A(29) A(30) A(31) \
  A(32) A(33) A(34) A(35) A(36) A(37) A(38) A(39) \
  A(40) A(41) A(42) A(43) A(44) A(45) A(46) A(47) \
  A(48) A(49) A(50) A(51) A(52) A(53) A(54) A(55) \
  A(56) A(57) A(58) A(59) A(60) A(61) A(62) A(63)

// 16 groups of 4 experts (for float4-wide LDS traffic)
#define FOR_G(G) G(0,0,1,2,3) G(1,4,5,6,7) G(2,8,9,10,11) G(3,12,13,14,15) \
  G(4,16,17,18,19) G(5,20,21,22,23) G(6,24,25,26,27) G(7,28,29,30,31) \
  G(8,32,33,34,35) G(9,36,37,38,39) G(10,40,41,42,43) G(11,44,45,46,47) \
  G(12,48,49,50,51) G(13,52,53,54,55) G(14,56,57,58,59) G(15,60,61,62,63)

#define DECL(e) float acc##e = 0.f;

#define FMAE(e) { \
  const float4* _wv = (const float4*)(Wb + (size_t)(e) * DM); \
  const float4 _w0 = _wv[0], _w1 = _wv[1], _w2 = _wv[2], _w3 = _wv[3]; \
  float _s = 0.f; \
  _s = fmaf(xw0.x, _w0.x, _s); _s = fmaf(xw0.y, _w0.y, _s); \
  _s = fmaf(xw0.z, _w0.z, _s); _s = fmaf(xw0.w, _w0.w, _s); \
  _s = fmaf(xw1.x, _w1.x, _s); _s = fmaf(xw1.y, _w1.y, _s); \
  _s = fmaf(xw1.z, _w1.z, _s); _s = fmaf(xw1.w, _w1.w, _s); \
  _s = fmaf(xw2.x, _w2.x, _s); _s = fmaf(xw2.y, _w2.y, _s); \
  _s = fmaf(xw2.z, _w2.z, _s); _s = fmaf(xw2.w, _w2.w, _s); \
  _s = fmaf(xw3.x, _w3.x, _s); _s = fmaf(xw3.y, _w3.y, _s); \
  _s = fmaf(xw3.z, _w3.z, _s); _s = fmaf(xw3.w, _w3.w, _s); \
  acc##e += _s; }

#define DUMPG(g,a,b,c,d) \
  *(float4*)&red[_slot][lane][4*(g)] = make_float4(acc##a, acc##b, acc##c, acc##d);
#define DUMP(s) { const int _slot = (s); FOR_G(DUMPG) }

#define ADDG(g,a,b,c,d) { \
  const float4 _t = *(const float4*)&red[_slot][lane][4*(g)]; \
  acc##a += _t.x; acc##b += _t.y; acc##c += _t.z; acc##d += _t.w; }
#define ADDIN(s) { const int _slot = (s); FOR_G(ADDG) }

#define SELE(e) { const bool _b = acc##e > _m; _m = _b ? acc##e : _m; _mi = _b ? (e) : _mi; }
#define CLRE(e) acc##e = (_mi == (e)) ? NEGINF : acc##e;
#define TOPP(p) { float _m = NEGINF; int _mi = 0; FOR_E(SELE) idx##p = _mi; FOR_E(CLRE) }

__global__ __launch_bounds__(512, 2) void gate_kernel(
    const float* __restrict__ x,
    const float* __restrict__ W,
    int* __restrict__ out) {

  const int lane = threadIdx.x & 63;
  const int wid  = __builtin_amdgcn_readfirstlane((int)(threadIdx.x >> 6));
  const int tok  = blockIdx.x * 64 + lane;
  const int kbase = wid * KCH;

  FOR_E(DECL)

  const float* xrow = x + (size_t)tok * DM + kbase;

  // double-buffered per-lane x window (16 floats as 4 named float4s)
  float4 xw0, xw1, xw2, xw3, xn0, xn1, xn2, xn3;
  {
    const float4* xp = (const float4*)xrow;
    xw0 = xp[0]; xw1 = xp[1]; xw2 = xp[2]; xw3 = xp[3];
  }

  for (int w = 0; w < NWIN; ++w) {
    if (w + 1 < NWIN) {
      const float4* xp = (const float4*)(xrow + (w + 1) * WIN);
      xn0 = xp[0]; xn1 = xp[1]; xn2 = xp[2]; xn3 = xp[3];
    }
    const float* Wb = W + kbase + w * WIN; // wave-uniform base
    FOR_E(FMAE)
    xw0 = xn0; xw1 = xn1; xw2 = xn2; xw3 = xn3;
  }

  // ---- cross-wave K reduction: pairwise tree via LDS (2 slots) ----
  __shared__ float red[2][64][68]; // 68-float stride, 16B-aligned rows, 34816 B

  if (wid == 4) DUMP(0)
  if (wid == 5) DUMP(1)
  __syncthreads();
  if (wid == 0) ADDIN(0)
  if (wid == 1) ADDIN(1)
  __syncthreads();
  if (wid == 6) DUMP(0)
  if (wid == 7) DUMP(1)
  __syncthreads();
  if (wid == 2) ADDIN(0)
  if (wid == 3) ADDIN(1)
  __syncthreads();
  if (wid == 2) DUMP(0)
  if (wid == 3) DUMP(1)
  __syncthreads();
  if (wid == 0) ADDIN(0)
  if (wid == 1) ADDIN(1)
  __syncthreads();
  if (wid == 1) DUMP(0)
  __syncthreads();

  if (wid == 0) {
    ADDIN(0)

    // ---- top-8 by repeated argmax (stable: lowest index wins ties) ----
    int idx0, idx1, idx2, idx3, idx4, idx5, idx6, idx7;
    TOPP(0) TOPP(1) TOPP(2) TOPP(3) TOPP(4) TOPP(5) TOPP(6) TOPP(7)

    int4* op = (int4*)(out + (size_t)tok * TOPK);
    op[0] = make_int4(idx0, idx1, idx2, idx3);
    op[1] = make_int4(idx4, idx5, idx6, idx7);
  }
}

extern "C" void kernel_launch(void* const* d_in, const int* in_sizes, int n_in,
                              void* d_out, int out_size, void* d_ws, size_t ws_size,
                              hipStream_t stream) {
  const float* x = (const float*)d_in[0];
  const float* W = (const float*)d_in[1];
  int* out = (int*)d_out;
  (void)in_sizes; (void)n_in; (void)out_size; (void)d_ws; (void)ws_size;

  dim3 grid(NT / 64);   // 256 workgroups, one per 64 tokens
  dim3 block(512);      // 8 waves: K-split
  hipLaunchKernelGGL(gate_kernel, grid, block, 0, stream, x, W, out);
}